// Round 3
// baseline (86.507 us; speedup 1.0000x reference)
//
#include <hip/hip_runtime.h>
#include <math.h>

#define NIMG 64
#define HW   1024
#define NCH  85
#define NCLS 80
#define NW   16     // waves per block
#define CPW  5      // classes per wave (16*5 = 80)
#define CONF_TH 0.25f
#define NMS_TH  0.35f

__device__ __forceinline__ float fast_tanh(float x) {
  float e = __expf(2.0f * x);
  return 1.0f - 2.0f * __builtin_amdgcn_rcpf(e + 1.0f);
}
__device__ __forceinline__ float fast_sigmoid(float x) {
  return __builtin_amdgcn_rcpf(1.0f + __expf(-x));
}

// Partial argmax over NC class channels starting at absolute channel CL0,
// for 4 consecutive pixels (float4 lanes). Ascending channel order + strict >
// == exact first-occurrence argmax within the quarter.  (verbatim from the
// proven 73.1us kernel)
template <int CL0, int NC>
__device__ __forceinline__ void quarter_argmax(const float* __restrict__ bp,
                                               float4& mv, int4& mi) {
  float4 v = *(const float4*)(bp + (size_t)CL0 * HW);
  float b0 = v.x, b1 = v.y, b2 = v.z, b3 = v.w;
  int i0 = CL0 - 5, i1 = i0, i2 = i0, i3 = i0;
#pragma unroll
  for (int c = 1; c < NC; ++c) {
    float4 u = *(const float4*)(bp + (size_t)(CL0 + c) * HW);
    int ci = CL0 - 5 + c;
    if (u.x > b0) { b0 = u.x; i0 = ci; }
    if (u.y > b1) { b1 = u.y; i1 = ci; }
    if (u.z > b2) { b2 = u.z; i2 = ci; }
    if (u.w > b3) { b3 = u.w; i3 = ci; }
  }
  mv = make_float4(b0, b1, b2, b3);
  mi = make_int4(i0, i1, i2, i3);
}

// ---------------------------------------------------------------------------
// Fused decode + class-aware NMS. One block per image, 1024 threads.
// Decode: identical to the proven kernel (float4 loads, channel quarters).
// NMS: NO block-wide phase ladder. After one stage barrier, each of the 16
// waves independently processes 5 classes with wave-local ops only (ballot
// member collection, uniform rank loop, lane-parallel greedy suppression).
// Barriers: 2 total (was 7). No atomics, no prefix scan, no scatter phase.
// ---------------------------------------------------------------------------
__global__ __launch_bounds__(1024) void fused_kernel(const float* __restrict__ preds,
                                                     float* __restrict__ out,
                                                     float* __restrict__ keepOut) {
  int n = blockIdx.x;
  int t = threadIdx.x;
  int q  = t >> 8;          // channel quarter (wave-uniform)
  int pg = t & 255;         // pixel group: pixels 4*pg .. 4*pg+3
  int wv   = t >> 6;        // wave id 0..15
  int lane = t & 63;

  __shared__ float sx1[HW], sy1[HW], sx2[HW], sy2[HW], sarea[HW], sscore[HW];
  __shared__ int scls[HW];
  __shared__ float pmaxv[4][HW];             // per-quarter partial max  [q][pixel]
  __shared__ int   pmaxi[4][HW];             // per-quarter partial argmax
  __shared__ float sobj[HW];
  __shared__ float sreg[4][HW];              // tx, ty, tw, th
  __shared__ unsigned short mlist[NW][HW];   // per-wave member list (pixel-asc)
  __shared__ unsigned short ssort[NW][64];   // per-wave rank->pixel (fast path)
  __shared__ unsigned long long wflags[NW][32]; // fallback: processed[0:16), kept[16:32)

  // ---- decode phase A: cooperative float4 channel loads ----
  const float* bp = preds + (size_t)n * (NCH * HW) + 4 * pg;
  float4 mv; int4 mi;
  if (q == 0) {
    float4 vobj = *(const float4*)(bp);
    ((float4*)sobj)[pg] = vobj;
#pragma unroll
    for (int r = 0; r < 4; ++r) {
      float4 vr = *(const float4*)(bp + (size_t)(1 + r) * HW);
      ((float4*)&sreg[r][0])[pg] = vr;
    }
    quarter_argmax<5, 16>(bp, mv, mi);     // classes  0..15
  } else if (q == 1) {
    quarter_argmax<21, 21>(bp, mv, mi);    // classes 16..36
  } else if (q == 2) {
    quarter_argmax<42, 21>(bp, mv, mi);    // classes 37..57
  } else {
    quarter_argmax<63, 22>(bp, mv, mi);    // classes 58..79
  }
  ((float4*)&pmaxv[q][0])[pg] = mv;
  ((int4*)&pmaxi[q][0])[pg] = mi;
  __syncthreads();

  // ---- decode phase B: per-pixel combine (ascending q, strict > ==
  //      exact first-occurrence across quarters) + box math ----
  float pobj = sobj[t];
  float tx = sreg[0][t], ty = sreg[1][t], tw = sreg[2][t], th = sreg[3][t];
  float best = pmaxv[0][t]; int bc = pmaxi[0][t];
#pragma unroll
  for (int qq = 1; qq < 4; ++qq) {
    float v = pmaxv[qq][t];
    if (v > best) { best = v; bc = pmaxi[qq][t]; }
  }
  float score = pobj * best;               // bit-exact vs reference

  float gx = (float)(t & 31);
  float gy = (float)(t >> 5);
  float bcx = (fast_tanh(tx) + gx) * 0.03125f;
  float bcy = (fast_tanh(ty) + gy) * 0.03125f;
  float bw = fast_sigmoid(tw);
  float bh = fast_sigmoid(th);

  float x1 = bcx - 0.5f * bw, y1 = bcy - 0.5f * bh;
  float x2 = bcx + 0.5f * bw, y2 = bcy + 0.5f * bh;

  size_t gb = (size_t)n * HW + t;
  float2* ob = (float2*)(out + gb * 6);    // fire-and-forget output store
  ob[0] = make_float2(x1, y1);
  ob[1] = make_float2(x2, y2);
  ob[2] = make_float2(score, (float)bc);

  sx1[t] = x1; sy1[t] = y1; sx2[t] = x2; sy2[t] = y2;
  sarea[t] = (x2 - x1) * (y2 - y1);
  sscore[t] = score;
  scls[t] = bc;
  keepOut[gb] = 0.0f;                      // drained by the barrier below,
  __syncthreads();                         // so later 1.0 stores order after it

  // ---- wave-local NMS: wave wv owns classes 5*wv .. 5*wv+4 ----
  // Preload this lane's 16 pixels' (cls, score) into registers.
  int   cls_r[16];
  float sc_r[16];
#pragma unroll
  for (int k = 0; k < 16; ++k) {
    int p = (k << 6) | lane;
    cls_r[k] = scls[p];
    sc_r[k]  = sscore[p];
  }

  for (int ci = 0; ci < CPW; ++ci) {
    int c = wv * CPW + ci;

    // -- collect members in pixel-ascending order (exact original order) --
    int m = 0;
#pragma unroll
    for (int k = 0; k < 16; ++k) {
      bool pred = (cls_r[k] == c) && (sc_r[k] > CONF_TH);
      unsigned long long mask = __ballot(pred);
      while (mask) {
        int l = __ffsll((unsigned long long)mask) - 1;
        mask &= mask - 1;
        if (lane == 0) mlist[wv][m] = (unsigned short)((k << 6) | l);
        ++m;                               // uniform across the wave
      }
    }
    if (m == 0) continue;

    if (m <= 64) {
      // -- rank: lane j owns member j; exact stable (score desc, idx asc) --
      int pj = 0; float scj = 0.0f; int rj = 0;
      bool active = (lane < m);
      if (active) { pj = mlist[wv][lane]; scj = sscore[pj]; }
      for (int i = 0; i < m; ++i) {
        int pi = mlist[wv][i];             // uniform LDS read (broadcast)
        float si = sscore[pi];
        if (active) rj += (si > scj) || (si == scj && pi < pj);
      }
      if (active) ssort[wv][rj] = (unsigned short)pj;

      // -- lane b caches the rank-b box --
      float kx1 = 0, ky1 = 0, kx2 = 0, ky2 = 0, kar = 0;
      if (active) {
        int qb = ssort[wv][lane];
        kx1 = sx1[qb]; ky1 = sy1[qb]; kx2 = sx2[qb]; ky2 = sy2[qb]; kar = sarea[qb];
      }

      // -- greedy scan in rank order: lane-parallel IoU vs kept, ballot --
      unsigned long long kept = 0ull;      // uniform in every lane
      for (int a = 0; a < m; ++a) {
        int qa = ssort[wv][a];             // uniform
        float ax1 = sx1[qa], ay1 = sy1[qa], ax2 = sx2[qa], ay2 = sy2[qa];
        float aar = sarea[qa];             // candidate area (first in denom)
        bool sup = false;
        if (lane < a && ((kept >> lane) & 1ull)) {
          float iw = fminf(ax2, kx2) - fmaxf(ax1, kx1);
          float ih = fminf(ay2, ky2) - fmaxf(ay1, ky1);
          iw = fmaxf(iw, 0.0f);
          ih = fmaxf(ih, 0.0f);
          float inter = iw * ih;
          float iou = inter / (aar + kar - inter + 1e-9f);  // exact ref op order
          sup = iou > NMS_TH;
        }
        unsigned long long v = __ballot(sup);
        if (v == 0ull) {
          kept |= (1ull << a);
          if (lane == 0) keepOut[(size_t)n * HW + qa] = 1.0f;
        }
      }
    } else {
      // -- capacity-complete exact fallback (Poisson mean ~6: never expected) --
      if (lane == 0) {
        for (int i = 0; i < 32; ++i) wflags[wv][i] = 0ull;
        for (int a = 0; a < m; ++a) {
          // selection: unprocessed member with max (score, -idx)
          int bj = -1; float bs = 0.0f; int bpx = 0;
          for (int j = 0; j < m; ++j) {
            if ((wflags[wv][j >> 6] >> (j & 63)) & 1ull) continue;
            int pj2 = mlist[wv][j];
            float sj2 = sscore[pj2];
            if (bj < 0 || sj2 > bs || (sj2 == bs && pj2 < bpx)) { bj = j; bs = sj2; bpx = pj2; }
          }
          wflags[wv][bj >> 6] |= 1ull << (bj & 63);
          float cx1 = sx1[bpx], cy1 = sy1[bpx], cx2 = sx2[bpx], cy2 = sy2[bpx];
          float car = sarea[bpx];
          bool kp = true;
          for (int j = 0; j < m && kp; ++j) {
            if (!((wflags[wv][16 + (j >> 6)] >> (j & 63)) & 1ull)) continue;
            int pj2 = mlist[wv][j];
            float iw = fminf(cx2, sx2[pj2]) - fmaxf(cx1, sx1[pj2]);
            float ih = fminf(cy2, sy2[pj2]) - fmaxf(cy1, sy1[pj2]);
            iw = fmaxf(iw, 0.0f);
            ih = fmaxf(ih, 0.0f);
            float inter = iw * ih;
            float iou = inter / (car + sarea[pj2] - inter + 1e-9f);
            if (iou > NMS_TH) kp = false;
          }
          if (kp) {
            wflags[wv][16 + (bj >> 6)] |= 1ull << (bj & 63);
            keepOut[(size_t)n * HW + bpx] = 1.0f;
          }
        }
      }
    }
  }
}

extern "C" void kernel_launch(void* const* d_in, const int* in_sizes, int n_in,
                              void* d_out, int out_size, void* d_ws, size_t ws_size,
                              hipStream_t stream) {
  const float* preds = (const float*)d_in[0];
  float* out = (float*)d_out;
  float* keepOut = out + (size_t)NIMG * HW * 6;

  fused_kernel<<<NIMG, HW, 0, stream>>>(preds, out, keepOut);
}